// Round 1
// baseline (38311.136 us; speedup 1.0000x reference)
//
#include <hip/hip_runtime.h>
#include <stdint.h>

#define NNODES 2048
#define T_SEQ  2048
#define HD     640
#define GD     2560   // 4*HD
#define KIN    8500
#define NEDGE  65536
#define NGRAPH 16

// fused_scan geometry: 3 layers x 32 blocks x 20 dims, 512 threads (8 waves)
#define LSB   32      // blocks per layer
#define LDIM  20      // h-dims per block
#define ROWU  1024    // u32 per record row (32 blocks x 32 u32, 128B line-padded)
#define RECN  (T_SEQ * ROWU)   // u32 per layer record buffer

typedef unsigned long long u64;
typedef _Float16 half2v __attribute__((ext_vector_type(2)));
using short8 = __attribute__((ext_vector_type(8))) short;
using f32x4  = __attribute__((ext_vector_type(4))) float;
using u32x4  = __attribute__((ext_vector_type(4))) unsigned int;

#if __has_builtin(__builtin_amdgcn_fdot2)
#define HAVE_FDOT2 1
#endif

__device__ __forceinline__ float dot2acc(unsigned w, unsigned h, float acc) {
#ifdef HAVE_FDOT2
  return __builtin_amdgcn_fdot2(__builtin_bit_cast(half2v, w),
                                __builtin_bit_cast(half2v, h), acc, false);
#else
  acc += (float)__builtin_bit_cast(_Float16, (unsigned short)(w & 0xffffu)) *
         (float)__builtin_bit_cast(_Float16, (unsigned short)(h & 0xffffu));
  acc += (float)__builtin_bit_cast(_Float16, (unsigned short)(w >> 16)) *
         (float)__builtin_bit_cast(_Float16, (unsigned short)(h >> 16));
  return acc;
#endif
}

__device__ __forceinline__ unsigned short f2h(float x) {
  return __builtin_bit_cast(unsigned short, (_Float16)x);
}
__device__ __forceinline__ unsigned packh(float a, float b) {
  return (unsigned)f2h(a) | ((unsigned)f2h(b) << 16);
}
__device__ __forceinline__ unsigned f2bf(float x) {
  unsigned u = __float_as_uint(x);
  return (u + 0x7fffu + ((u >> 16) & 1u)) >> 16;
}
__device__ __forceinline__ unsigned packbf(float a, float b) {
  return f2bf(a) | (f2bf(b) << 16);
}

// full-wave64 f32 sum; total lands in lane 63 (GCN DPP reduce sequence)
__device__ __forceinline__ float wave_red(float x) {
#define RSTEP(ctrl)                                                           \
  {                                                                           \
    int vv_ = __builtin_bit_cast(int, x);                                     \
    x += __builtin_bit_cast(                                                  \
        float, __builtin_amdgcn_update_dpp(0, vv_, ctrl, 0xf, 0xf, true));    \
  }
  RSTEP(0x111)  // row_shr:1
  RSTEP(0x112)  // row_shr:2
  RSTEP(0x114)  // row_shr:4
  RSTEP(0x118)  // row_shr:8
  RSTEP(0x142)  // row_bcast:15
  RSTEP(0x143)  // row_bcast:31
#undef RSTEP
  return x;
}

// XCD-local (L2-coherent, bypass L1) 16B load
__device__ __forceinline__ u32x4 load16_sc0(const unsigned* p) {
  u32x4 v;
  asm volatile("global_load_dwordx4 %0, %1, off sc0\n\ts_waitcnt vmcnt(0)"
               : "=v"(v) : "v"(p) : "memory");
  return v;
}
// device-coherent (Infinity-Cache) 16B load
__device__ __forceinline__ u32x4 load16_agent(const unsigned* p) {
  u64 a = __hip_atomic_load((const u64*)p, __ATOMIC_RELAXED,
                            __HIP_MEMORY_SCOPE_AGENT);
  u64 b = __hip_atomic_load((const u64*)p + 1, __ATOMIC_RELAXED,
                            __HIP_MEMORY_SCOPE_AGENT);
  u32x4 v;
  v.x = (unsigned)a; v.y = (unsigned)(a >> 32);
  v.z = (unsigned)b; v.w = (unsigned)(b >> 32);
  return v;
}
__device__ __forceinline__ void store_u32_sc0(unsigned* p, unsigned v) {
  asm volatile("global_store_dword %0, %1, off sc0" ::"v"(p), "v"(v)
               : "memory");
}

// ---------------------------------------------------------------------------
// C[M,N] = A[M,K] @ W[N,K]^T + b1[n] + b2[n], bf16 MFMA 16x16x32. (unchanged)
// ---------------------------------------------------------------------------
#define GK 32
__global__ __launch_bounds__(256) void gemm_mfma(
    const float* __restrict__ A, const float* __restrict__ W,
    const float* __restrict__ b1, const float* __restrict__ b2,
    float* __restrict__ C, int M, int N, int K) {
  __shared__ __align__(16) short As[128 * 40];
  __shared__ __align__(16) short Ws[128 * 40];
  const int tid = threadIdx.x;
  const int wave = tid >> 6, lane = tid & 63;
  const int bm = blockIdx.y * 128, bn = blockIdx.x * 128;
  const int wm = (wave >> 1) * 64, wn = (wave & 1) * 64;
  const int mrow = lane & 15, quad = lane >> 4;
  const int srow = tid >> 1, skc = (tid & 1) * 16;
  f32x4 acc[4][4] = {};
  for (int k0 = 0; k0 < K; k0 += GK) {
    float av[16], wv[16];
    if (k0 + GK <= K) {
      const float* Ap = A + (long)(bm + srow) * K + k0 + skc;
      const float* Wp = W + (long)(bn + srow) * K + k0 + skc;
#pragma unroll
      for (int i = 0; i < 4; i++) {
        float4 a4 = *(const float4*)(Ap + 4 * i);
        float4 w4 = *(const float4*)(Wp + 4 * i);
        av[4*i]=a4.x; av[4*i+1]=a4.y; av[4*i+2]=a4.z; av[4*i+3]=a4.w;
        wv[4*i]=w4.x; wv[4*i+1]=w4.y; wv[4*i+2]=w4.z; wv[4*i+3]=w4.w;
      }
    } else {
#pragma unroll
      for (int i = 0; i < 16; i++) {
        const int k = k0 + skc + i;
        av[i] = (k < K) ? A[(long)(bm + srow) * K + k] : 0.f;
        wv[i] = (k < K) ? W[(long)(bn + srow) * K + k] : 0.f;
      }
    }
    __syncthreads();
    {
      uint4* pa = (uint4*)&As[srow * 40 + skc];
      uint4* pw = (uint4*)&Ws[srow * 40 + skc];
      pa[0] = make_uint4(packbf(av[0],av[1]), packbf(av[2],av[3]),
                         packbf(av[4],av[5]), packbf(av[6],av[7]));
      pa[1] = make_uint4(packbf(av[8],av[9]), packbf(av[10],av[11]),
                         packbf(av[12],av[13]), packbf(av[14],av[15]));
      pw[0] = make_uint4(packbf(wv[0],wv[1]), packbf(wv[2],wv[3]),
                         packbf(wv[4],wv[5]), packbf(wv[6],wv[7]));
      pw[1] = make_uint4(packbf(wv[8],wv[9]), packbf(wv[10],wv[11]),
                         packbf(wv[12],wv[13]), packbf(wv[14],wv[15]));
    }
    __syncthreads();
    short8 af[4], bf[4];
#pragma unroll
    for (int mi = 0; mi < 4; mi++)
      af[mi] = *(const short8*)&As[(wm + mi * 16 + mrow) * 40 + quad * 8];
#pragma unroll
    for (int ni = 0; ni < 4; ni++)
      bf[ni] = *(const short8*)&Ws[(wn + ni * 16 + mrow) * 40 + quad * 8];
#pragma unroll
    for (int mi = 0; mi < 4; mi++)
#pragma unroll
      for (int ni = 0; ni < 4; ni++)
        acc[mi][ni] = __builtin_amdgcn_mfma_f32_16x16x32_bf16(
            af[mi], bf[ni], acc[mi][ni], 0, 0, 0);
  }
#pragma unroll
  for (int ni = 0; ni < 4; ni++) {
    const int c = bn + wn + ni * 16 + mrow;
    const float bias = b1[c] + b2[c];
#pragma unroll
    for (int mi = 0; mi < 4; mi++) {
      const int r0 = bm + wm + mi * 16 + quad * 4;
#pragma unroll
      for (int reg = 0; reg < 4; reg++)
        C[(long)(r0 + reg) * N + c] = acc[mi][ni][reg] + bias;
    }
  }
}

// ---------------------------------------------------------------------------
// Fused 3-layer pipelined LSTM scan, XCD-local communication.
// Layer l -> blocks with blockIdx%8==l (one XCD under round-robin dispatch).
// 32 blocks/layer x 20 dims; weights in registers (f16 pairs, 100 VGPR/thr).
// Records: u32 per dim = f16(h) | seq<<16; rows padded to 32 u32 per block so
// no 64B line is shared across blocks (safe under any XCD placement).
// Writers dual-store: sc0 (XCD L2, fast local) + agent (IF, always correct).
// Readers pick sc0 vs agent per-source via XCC_ID handshake; any sc0 reader
// that stalls past a spin cap permanently escalates to agent scope.
// ---------------------------------------------------------------------------
__global__ __launch_bounds__(512, 2) void fused_scan(
    const float* __restrict__ xp,
    const float* __restrict__ whh0,
    const float* __restrict__ wih1, const float* __restrict__ whh1,
    const float* __restrict__ bih1, const float* __restrict__ bhh1,
    const float* __restrict__ wih2, const float* __restrict__ whh2,
    const float* __restrict__ bih2, const float* __restrict__ bhh2,
    unsigned* __restrict__ rec0, unsigned* __restrict__ rec1,
    unsigned* __restrict__ rec2, unsigned* __restrict__ xcdmap,
    float* __restrict__ hs2) {
  const int l = blockIdx.x & 7;
  if (l >= 3) return;                       // residues 3..7 idle
  const int blk = blockIdx.x >> 3;          // 0..31 within layer
  const int tid = threadIdx.x, wv = tid >> 6, lane = tid & 63;

  unsigned xcc;
  asm volatile("s_getreg_b32 %0, hwreg(20, 0, 32)" : "=s"(xcc));  // XCC_ID
  xcc &= 0xffu;
  if (tid == 0)
    __hip_atomic_store(&xcdmap[l * LSB + blk], 0x100u | xcc,
                       __ATOMIC_RELAXED, __HIP_MEMORY_SCOPE_AGENT);

  __shared__ unsigned hbuf32[320];   // 640 f16 h (own layer, t-1)
  __shared__ unsigned xbuf32[320];   // 640 f16 x (upstream, t)
  __shared__ float pdot[80];         // row sums: r = g*20 + d

  const float* Wih = (l == 1) ? wih1 : wih2;
  const float* Whh = (l == 0) ? whh0 : ((l == 1) ? whh1 : whh2);
  const float* bi  = (l == 1) ? bih1 : bih2;
  const float* bh  = (l == 1) ? bhh1 : bhh2;
  unsigned* recL = (l == 0) ? rec0 : ((l == 1) ? rec1 : rec2);
  const unsigned* recU = (l == 1) ? rec0 : rec1;

  // ---- stage weights into registers. wave wv: gate g=wv>>1, dims d0..d0+9.
  // lane k-chunk: [10*lane, 10*lane+10) as 5 packed f16 pairs.
  const int g = wv >> 1, d0 = 10 * (wv & 1);
  const int row0 = g * HD + blk * LDIM + d0;
  unsigned wh[10][5], wx[10][5];
#pragma unroll
  for (int ri = 0; ri < 10; ++ri) {
    const float* wr = Whh + (long)(row0 + ri) * HD + 10 * lane;
#pragma unroll
    for (int i = 0; i < 5; ++i) {
      float2 a = *(const float2*)(wr + 2 * i);
      wh[ri][i] = packh(a.x, a.y);
    }
  }
  if (l > 0) {
#pragma unroll
    for (int ri = 0; ri < 10; ++ri) {
      const float* wr = Wih + (long)(row0 + ri) * HD + 10 * lane;
#pragma unroll
      for (int i = 0; i < 5; ++i) {
        float2 a = *(const float2*)(wr + 2 * i);
        wx[ri][i] = packh(a.x, a.y);
      }
    }
  }

  // ---- gate lanes (wave 0, lane<20): per-dim external terms + cell state
  const int myd = blk * LDIM + lane;
  float ext[4] = {0.f, 0.f, 0.f, 0.f}, bsum[4] = {0.f, 0.f, 0.f, 0.f};
  float creg = 0.f;
  if (wv == 0 && lane < LDIM) {
    if (l == 0) {
#pragma unroll
      for (int q = 0; q < 4; ++q) ext[q] = xp[q * HD + myd];   // t = 0
    } else {
#pragma unroll
      for (int q = 0; q < 4; ++q) bsum[q] = bi[q * HD + myd] + bh[q * HD + myd];
    }
  }

  for (int i = tid; i < 320; i += 512) { hbuf32[i] = 0; xbuf32[i] = 0; }

  // ---- poll-lane geometry: wave wv covers dims [80*wv, 80*wv+80)
  // lanes 0..19 poll own layer (t-1); lanes 32..51 poll upstream (t), l>0.
  const bool isA = (lane < LDIM);
  const bool isB = (l > 0) && (lane >= 32) && (lane < 32 + LDIM);
  const int pp = isA ? lane : (lane - 32);
  const int dimoff = 80 * wv + 4 * pp;           // first of 4 polled h-dims
  const int srcblk = dimoff / LDIM;              // producing block
  const int sloto = dimoff + 12 * srcblk;        // padded slot in record row

  bool local = false;
  if (isA || isB) {
    const int maprow = isA ? l : (l - 1);
    const unsigned* me = &xcdmap[maprow * LSB + srcblk];
    unsigned e = 0;
    for (int c = 0; c < 100000; ++c) {
      e = __hip_atomic_load(me, __ATOMIC_RELAXED, __HIP_MEMORY_SCOPE_AGENT);
      if (e) break;
    }
    local = (e != 0) && ((e & 0xffu) == xcc);
  }
  __syncthreads();

  long totspins = 0;
  for (int t = 0; t < T_SEQ; ++t) {
    // ---- poll + unpack (own-layer lanes and upstream lanes in parallel)
    const bool want = (isA && t > 0) || isB;
    if (want && totspins < 80000000L) {
      const unsigned expseq = isA ? (unsigned)t : (unsigned)(t + 1);
      const unsigned* src = isA ? (recL + (long)(t - 1) * ROWU + sloto)
                                : (recU + (long)t * ROWU + sloto);
      unsigned* dst = (isA ? hbuf32 : xbuf32) + (dimoff >> 1);
      int ss = 0;
      for (;;) {
        u32x4 v;
        if (local) v = load16_sc0(src);
        else       v = load16_agent(src);
        if ((v.x >> 16) == expseq && (v.y >> 16) == expseq &&
            (v.z >> 16) == expseq && (v.w >> 16) == expseq) {
          dst[0] = (v.x & 0xffffu) | (v.y << 16);
          dst[1] = (v.z & 0xffffu) | (v.w << 16);
          break;
        }
        ++ss; ++totspins;
        if (local) {
          if (ss > 4096) local = false;   // escalate: wrong placement/coherence
        } else {
          __builtin_amdgcn_s_sleep(1);
        }
        if (totspins > 80000000L) break;  // safety: wrong > hung
      }
    }
    __syncthreads();   // hbuf/xbuf complete

    // ---- dot: 10 rows x full k; lane k-chunk [10*lane, 10*lane+10)
    unsigned hc[5], xc[5] = {0, 0, 0, 0, 0};
#pragma unroll
    for (int i = 0; i < 5; ++i) hc[i] = hbuf32[5 * lane + i];
    if (l > 0) {
#pragma unroll
      for (int i = 0; i < 5; ++i) xc[i] = xbuf32[5 * lane + i];
    }
    float sum[10];
#pragma unroll
    for (int ri = 0; ri < 10; ++ri) {
      float a = 0.f;
#pragma unroll
      for (int i = 0; i < 5; ++i) a = dot2acc(wh[ri][i], hc[i], a);
      if (l > 0) {
#pragma unroll
        for (int i = 0; i < 5; ++i) a = dot2acc(wx[ri][i], xc[i], a);
      }
      sum[ri] = wave_red(a);
    }
    if (lane == 63) {
#pragma unroll
      for (int ri = 0; ri < 10; ++ri) pdot[10 * wv + ri] = sum[ri];
    }
    __syncthreads();   // pdot ready

    // ---- gates: wave 0, lane<20 computes all 4 gates of its dim (no shfl)
    if (wv == 0 && lane < LDIM) {
      float gs[4];
#pragma unroll
      for (int q = 0; q < 4; ++q)
        gs[q] = pdot[q * LDIM + lane] + ((l == 0) ? ext[q] : bsum[q]);
      const float ai = 1.f / (1.f + __expf(-gs[0]));
      const float af = 1.f / (1.f + __expf(-gs[1]));
      const float eg = __expf(2.f * gs[2]);
      const float ag = 1.f - 2.f / (eg + 1.f);
      const float ao = 1.f / (1.f + __expf(-gs[3]));
      creg = af * creg + ai * ag;
      const float ec = __expf(2.f * creg);
      const float h = ao * (1.f - 2.f / (ec + 1.f));
      const unsigned val = (unsigned)f2h(h) | ((unsigned)(t + 1) << 16);
      unsigned* wp = recL + (long)t * ROWU + blk * 32 + lane;
      store_u32_sc0(wp, val);                                   // XCD-local
      __hip_atomic_store(wp, val, __ATOMIC_RELAXED,
                         __HIP_MEMORY_SCOPE_AGENT);             // IF push
      if (l == 2) hs2[(long)t * HD + myd] = h;
      if (l == 0 && t + 1 < T_SEQ) {
#pragma unroll
        for (int q = 0; q < 4; ++q)
          ext[q] = xp[(long)(t + 1) * GD + q * HD + myd];       // prefetch
      }
    }
  }
}

// ---------------------------------------------------------------------------
// GCN pieces (unchanged)
// ---------------------------------------------------------------------------
__global__ __launch_bounds__(256) void gcn_gemm(
    const float* __restrict__ X, const float* __restrict__ W,
    float* __restrict__ Y, int di, int dout) {
  __shared__ float xr[640];
  const int n = blockIdx.x;
  for (int k = threadIdx.x; k < di; k += 256) xr[k] = X[(long)n * di + k];
  __syncthreads();
  for (int c = threadIdx.x; c < dout; c += 256) {
    float acc = 0.f;
    for (int k = 0; k < di; k++) acc = fmaf(xr[k], W[(long)k * dout + c], acc);
    Y[(long)n * dout + c] = acc;
  }
}

__global__ void deg_kernel(const int* __restrict__ dst, unsigned int* __restrict__ deg) {
  const int e = blockIdx.x * 256 + threadIdx.x;
  if (e < NEDGE) atomicAdd(&deg[dst[e]], 1u);
}

__global__ void dinv_kernel(const unsigned int* __restrict__ deg, float* __restrict__ dinv) {
  const int n = blockIdx.x * 256 + threadIdx.x;
  if (n < NNODES) dinv[n] = 1.f / sqrtf((float)(deg[n] + 1u));
}

__global__ __launch_bounds__(128) void gcn_scatter(
    const float* __restrict__ XW, const int* __restrict__ src,
    const int* __restrict__ dst, const float* __restrict__ dinv,
    float* __restrict__ out, int dout) {
  const int e = blockIdx.x;
  const int s = src[e], d = dst[e];
  const float nrm = dinv[s] * dinv[d];
  for (int c = threadIdx.x; c < dout; c += 128)
    atomicAdd(&out[(long)d * dout + c], XW[(long)s * dout + c] * nrm);
}

__global__ __launch_bounds__(256) void gcn_bn(
    const float* __restrict__ scat, const float* __restrict__ xw,
    const float* __restrict__ dinv, const float* __restrict__ bias,
    float* __restrict__ out, int dout) {
  const int c = blockIdx.x;
  const float bc = bias[c];
  float s = 0.f, s2 = 0.f;
  for (int n = threadIdx.x; n < NNODES; n += 256) {
    float v = scat[(long)n * dout + c] + xw[(long)n * dout + c] * dinv[n] * dinv[n] + bc;
    v = v >= 0.f ? v : 0.01f * v;
    s += v; s2 += v * v;
  }
  __shared__ float rs[4], rs2[4];
#pragma unroll
  for (int off = 32; off; off >>= 1) { s += __shfl_down(s, off, 64); s2 += __shfl_down(s2, off, 64); }
  const int w = threadIdx.x >> 6;
  if ((threadIdx.x & 63) == 0) { rs[w] = s; rs2[w] = s2; }
  __syncthreads();
  const float ts  = rs[0] + rs[1] + rs[2] + rs[3];
  const float ts2 = rs2[0] + rs2[1] + rs2[2] + rs2[3];
  const float mu = ts * (1.f / (float)NNODES);
  const float var = ts2 * (1.f / (float)NNODES) - mu * mu;
  const float rstd = 1.f / sqrtf(var + 1e-5f);
  for (int n = threadIdx.x; n < NNODES; n += 256) {
    float v = scat[(long)n * dout + c] + xw[(long)n * dout + c] * dinv[n] * dinv[n] + bc;
    v = v >= 0.f ? v : 0.01f * v;
    out[(long)n * dout + c] = (v - mu) * rstd;
  }
}

__global__ __launch_bounds__(64) void pool_kernel(
    const float* __restrict__ x, float* __restrict__ emb, float* __restrict__ dout) {
  const int g = blockIdx.x, c = threadIdx.x;
  if (c >= 50) return;
  float s = 0.f;
  for (int r = 0; r < 128; r++) s += x[(long)(g * 128 + r) * 50 + c];
  emb[g * 50 + c] = s;
  dout[16 + g * 50 + c] = s;
}

__global__ __launch_bounds__(64) void fc_head(
    const float* __restrict__ emb,
    const float* __restrict__ w1, const float* __restrict__ b1,
    const float* __restrict__ w2, const float* __restrict__ b2,
    const float* __restrict__ w3, const float* __restrict__ b3,
    float* __restrict__ dout) {
  const int g = threadIdx.x;
  if (g >= NGRAPH) return;
  float e[50];
#pragma unroll
  for (int k = 0; k < 50; k++) e[k] = emb[g * 50 + k];
  float t1[32];
  for (int j = 0; j < 32; j++) {
    float a = b1[j];
    for (int k = 0; k < 50; k++) a = fmaf(e[k], w1[k * 32 + j], a);
    t1[j] = a;
  }
  float t2[16];
  for (int j = 0; j < 16; j++) {
    float a = b2[j];
    for (int k = 0; k < 32; k++) a = fmaf(t1[k], w2[k * 16 + j], a);
    t2[j] = a;
  }
  float y = b3[0];
  for (int k = 0; k < 16; k++) y = fmaf(t2[k], w3[k], y);
  dout[g] = y;
}

// ---------------------------------------------------------------------------
extern "C" void kernel_launch(void* const* d_in, const int* in_sizes, int n_in,
                              void* d_out, int out_size, void* d_ws, size_t ws_size,
                              hipStream_t stream) {
  const float* x_in  = (const float*)d_in[0];
  const int*   eidx  = (const int*)d_in[1];
  const float* w_ih[3] = {(const float*)d_in[2], (const float*)d_in[6],  (const float*)d_in[10]};
  const float* w_hh[3] = {(const float*)d_in[3], (const float*)d_in[7],  (const float*)d_in[11]};
  const float* b_ih[3] = {(const float*)d_in[4], (const float*)d_in[8],  (const float*)d_in[12]};
  const float* b_hh[3] = {(const float*)d_in[5], (const float*)d_in[9],  (const float*)d_in[13]};
  const float* gw[4] = {(const float*)d_in[14], (const float*)d_in[16], (const float*)d_in[18], (const float*)d_in[20]};
  const float* gbv[4] = {(const float*)d_in[15], (const float*)d_in[17], (const float*)d_in[19], (const float*)d_in[21]};
  const float* fw1 = (const float*)d_in[22]; const float* fb1 = (const float*)d_in[23];
  const float* fw2 = (const float*)d_in[24]; const float* fb2 = (const float*)d_in[25];
  const float* fw3 = (const float*)d_in[26]; const float* fb3 = (const float*)d_in[27];
  const int* src = eidx;
  const int* dst = eidx + NEDGE;

  // workspace layout (floats)
  float* ws  = (float*)d_ws;
  float* xp  = ws;                                   // 5,242,880
  unsigned* rec0 = (unsigned*)(ws + 5242880);        // 2,097,152 u32 each
  unsigned* rec1 = rec0 + RECN;
  unsigned* rec2 = rec1 + RECN;
  float* hs2 = ws + 5242880 + 3 * RECN;              // 1,310,720
  unsigned int* deg = (unsigned int*)(hs2 + 1310720);
  float* dinv = (float*)(deg + 2048);
  float* emb  = dinv + 2048;
  unsigned* xcdmap = (unsigned*)(emb + 800);         // 96 u32
  // GCN buffers alias the (then-dead) xp region
  float* ga = xp;
  float* gb = xp + 655360;
  float* x0 = xp + 1310720;
  float* x1 = xp + 1966080;

  hipMemsetAsync(rec0, 0, (size_t)3 * RECN * sizeof(unsigned), stream);
  hipMemsetAsync(xcdmap, 0, 96 * sizeof(unsigned), stream);
  hipMemsetAsync(deg, 0, 2048 * sizeof(unsigned int), stream);

  gemm_mfma<<<dim3(GD / 128, NNODES / 128), 256, 0, stream>>>(
      x_in, w_ih[0], b_ih[0], b_hh[0], xp, NNODES, GD, KIN);

  deg_kernel<<<NEDGE / 256, 256, 0, stream>>>(dst, deg);
  dinv_kernel<<<NNODES / 256, 256, 0, stream>>>(deg, dinv);

  fused_scan<<<256, 512, 0, stream>>>(
      xp, w_hh[0], w_ih[1], w_hh[1], b_ih[1], b_hh[1],
      w_ih[2], w_hh[2], b_ih[2], b_hh[2],
      rec0, rec1, rec2, xcdmap, hs2);

  const int dims_in[4]  = {640, 320, 180, 90};
  const int dims_out[4] = {320, 180, 90, 50};
  const float* xin_l[4] = {hs2, x0, x1, x0};
  float* xout_l[4]      = {x0, x1, x0, x1};
  for (int l = 0; l < 4; l++) {
    gcn_gemm<<<NNODES, 256, 0, stream>>>(xin_l[l], gw[l], ga, dims_in[l], dims_out[l]);
    hipMemsetAsync(gb, 0, (size_t)NNODES * dims_out[l] * sizeof(float), stream);
    gcn_scatter<<<NEDGE, 128, 0, stream>>>(ga, src, dst, dinv, gb, dims_out[l]);
    gcn_bn<<<dims_out[l], 256, 0, stream>>>(gb, ga, dinv, gbv[l], xout_l[l], dims_out[l]);
  }

  pool_kernel<<<NGRAPH, 64, 0, stream>>>(x1, emb, (float*)d_out);
  fc_head<<<1, 64, 0, stream>>>(emb, fw1, fb1, fw2, fb2, fw3, fb3, (float*)d_out);
}

// Round 2
// 13415.384 us; speedup vs baseline: 2.8558x; 2.8558x over previous
//
#include <hip/hip_runtime.h>
#include <stdint.h>

#define NNODES 2048
#define T_SEQ  2048
#define HD     640
#define GD     2560   // 4*HD
#define KIN    8500
#define NEDGE  65536
#define NGRAPH 16

// fused_scan geometry: 3 layers x 32 blocks x 20 dims, 512 threads (8 waves)
#define LSB   32      // blocks per layer
#define LDIM  20      // h-dims per block
#define ROWU  1024    // u32 per record row (32 blocks x 32 u32, 128B line-padded)
#define RECN  (T_SEQ * ROWU)   // u32 per layer record buffer

typedef unsigned long long u64;
typedef _Float16 half2v __attribute__((ext_vector_type(2)));
using short8 = __attribute__((ext_vector_type(8))) short;
using f32x4  = __attribute__((ext_vector_type(4))) float;
using u32x4  = __attribute__((ext_vector_type(4))) unsigned int;

#if __has_builtin(__builtin_amdgcn_fdot2)
#define HAVE_FDOT2 1
#endif

__device__ __forceinline__ float dot2acc(unsigned w, unsigned h, float acc) {
#ifdef HAVE_FDOT2
  return __builtin_amdgcn_fdot2(__builtin_bit_cast(half2v, w),
                                __builtin_bit_cast(half2v, h), acc, false);
#else
  acc += (float)__builtin_bit_cast(_Float16, (unsigned short)(w & 0xffffu)) *
         (float)__builtin_bit_cast(_Float16, (unsigned short)(h & 0xffffu));
  acc += (float)__builtin_bit_cast(_Float16, (unsigned short)(w >> 16)) *
         (float)__builtin_bit_cast(_Float16, (unsigned short)(h >> 16));
  return acc;
#endif
}

__device__ __forceinline__ unsigned short f2h(float x) {
  return __builtin_bit_cast(unsigned short, (_Float16)x);
}
__device__ __forceinline__ unsigned packh(float a, float b) {
  return (unsigned)f2h(a) | ((unsigned)f2h(b) << 16);
}
__device__ __forceinline__ unsigned f2bf(float x) {
  unsigned u = __float_as_uint(x);
  return (u + 0x7fffu + ((u >> 16) & 1u)) >> 16;
}
__device__ __forceinline__ unsigned packbf(float a, float b) {
  return f2bf(a) | (f2bf(b) << 16);
}

// full-wave64 f32 sum; total lands in lane 63 (GCN DPP reduce sequence)
__device__ __forceinline__ float wave_red(float x) {
#define RSTEP(ctrl)                                                           \
  {                                                                           \
    int vv_ = __builtin_bit_cast(int, x);                                     \
    x += __builtin_bit_cast(                                                  \
        float, __builtin_amdgcn_update_dpp(0, vv_, ctrl, 0xf, 0xf, true));    \
  }
  RSTEP(0x111)  // row_shr:1
  RSTEP(0x112)  // row_shr:2
  RSTEP(0x114)  // row_shr:4
  RSTEP(0x118)  // row_shr:8
  RSTEP(0x142)  // row_bcast:15
  RSTEP(0x143)  // row_bcast:31
#undef RSTEP
  return x;
}

// XCD-local (L2-coherent, bypass L1) 16B load
__device__ __forceinline__ u32x4 load16_sc0(const unsigned* p) {
  u32x4 v;
  asm volatile("global_load_dwordx4 %0, %1, off sc0\n\ts_waitcnt vmcnt(0)"
               : "=v"(v) : "v"(p) : "memory");
  return v;
}
// device-coherent (Infinity-Cache) 16B load
__device__ __forceinline__ u32x4 load16_agent(const unsigned* p) {
  u64 a = __hip_atomic_load((const u64*)p, __ATOMIC_RELAXED,
                            __HIP_MEMORY_SCOPE_AGENT);
  u64 b = __hip_atomic_load((const u64*)p + 1, __ATOMIC_RELAXED,
                            __HIP_MEMORY_SCOPE_AGENT);
  u32x4 v;
  v.x = (unsigned)a; v.y = (unsigned)(a >> 32);
  v.z = (unsigned)b; v.w = (unsigned)(b >> 32);
  return v;
}

// ---------------------------------------------------------------------------
// C[M,N] = A[M,K] @ W[N,K]^T + b1[n] + b2[n], bf16 MFMA 16x16x32. (unchanged)
// ---------------------------------------------------------------------------
#define GK 32
__global__ __launch_bounds__(256) void gemm_mfma(
    const float* __restrict__ A, const float* __restrict__ W,
    const float* __restrict__ b1, const float* __restrict__ b2,
    float* __restrict__ C, int M, int N, int K) {
  __shared__ __align__(16) short As[128 * 40];
  __shared__ __align__(16) short Ws[128 * 40];
  const int tid = threadIdx.x;
  const int wave = tid >> 6, lane = tid & 63;
  const int bm = blockIdx.y * 128, bn = blockIdx.x * 128;
  const int wm = (wave >> 1) * 64, wn = (wave & 1) * 64;
  const int mrow = lane & 15, quad = lane >> 4;
  const int srow = tid >> 1, skc = (tid & 1) * 16;
  f32x4 acc[4][4] = {};
  for (int k0 = 0; k0 < K; k0 += GK) {
    float av[16], wv[16];
    if (k0 + GK <= K) {
      const float* Ap = A + (long)(bm + srow) * K + k0 + skc;
      const float* Wp = W + (long)(bn + srow) * K + k0 + skc;
#pragma unroll
      for (int i = 0; i < 4; i++) {
        float4 a4 = *(const float4*)(Ap + 4 * i);
        float4 w4 = *(const float4*)(Wp + 4 * i);
        av[4*i]=a4.x; av[4*i+1]=a4.y; av[4*i+2]=a4.z; av[4*i+3]=a4.w;
        wv[4*i]=w4.x; wv[4*i+1]=w4.y; wv[4*i+2]=w4.z; wv[4*i+3]=w4.w;
      }
    } else {
#pragma unroll
      for (int i = 0; i < 16; i++) {
        const int k = k0 + skc + i;
        av[i] = (k < K) ? A[(long)(bm + srow) * K + k] : 0.f;
        wv[i] = (k < K) ? W[(long)(bn + srow) * K + k] : 0.f;
      }
    }
    __syncthreads();
    {
      uint4* pa = (uint4*)&As[srow * 40 + skc];
      uint4* pw = (uint4*)&Ws[srow * 40 + skc];
      pa[0] = make_uint4(packbf(av[0],av[1]), packbf(av[2],av[3]),
                         packbf(av[4],av[5]), packbf(av[6],av[7]));
      pa[1] = make_uint4(packbf(av[8],av[9]), packbf(av[10],av[11]),
                         packbf(av[12],av[13]), packbf(av[14],av[15]));
      pw[0] = make_uint4(packbf(wv[0],wv[1]), packbf(wv[2],wv[3]),
                         packbf(wv[4],wv[5]), packbf(wv[6],wv[7]));
      pw[1] = make_uint4(packbf(wv[8],wv[9]), packbf(wv[10],wv[11]),
                         packbf(wv[12],wv[13]), packbf(wv[14],wv[15]));
    }
    __syncthreads();
    short8 af[4], bf[4];
#pragma unroll
    for (int mi = 0; mi < 4; mi++)
      af[mi] = *(const short8*)&As[(wm + mi * 16 + mrow) * 40 + quad * 8];
#pragma unroll
    for (int ni = 0; ni < 4; ni++)
      bf[ni] = *(const short8*)&Ws[(wn + ni * 16 + mrow) * 40 + quad * 8];
#pragma unroll
    for (int mi = 0; mi < 4; mi++)
#pragma unroll
      for (int ni = 0; ni < 4; ni++)
        acc[mi][ni] = __builtin_amdgcn_mfma_f32_16x16x32_bf16(
            af[mi], bf[ni], acc[mi][ni], 0, 0, 0);
  }
#pragma unroll
  for (int ni = 0; ni < 4; ni++) {
    const int c = bn + wn + ni * 16 + mrow;
    const float bias = b1[c] + b2[c];
#pragma unroll
    for (int mi = 0; mi < 4; mi++) {
      const int r0 = bm + wm + mi * 16 + quad * 4;
#pragma unroll
      for (int reg = 0; reg < 4; reg++)
        C[(long)(r0 + reg) * N + c] = acc[mi][ni][reg] + bias;
    }
  }
}

// ---------------------------------------------------------------------------
// Fused 3-layer pipelined LSTM scan, XCD-local communication.
// Layer l -> blocks with blockIdx%8==l (one XCD under round-robin dispatch).
// 32 blocks/layer x 20 dims; weights in registers (f16 pairs, ~100 VGPR/thr;
// __launch_bounds__(512) WITHOUT min-waves so the cap is high enough — the
// round-1 (512,2) variant capped VGPRs at 128 and spilled the weights).
// Records: u32 per dim = f16(h) | seq<<16; rows padded to 32 u32 per block.
// Writer: ONE agent-scope store (write-through local L2 -> visible to both
// same-XCD sc0 readers and remote agent readers).
// Readers pick sc0 vs agent per-source via XCC_ID handshake; any sc0 reader
// that stalls past a spin cap permanently escalates to agent scope.
// ---------------------------------------------------------------------------
__global__ __launch_bounds__(512) void fused_scan(
    const float* __restrict__ xp,
    const float* __restrict__ whh0,
    const float* __restrict__ wih1, const float* __restrict__ whh1,
    const float* __restrict__ bih1, const float* __restrict__ bhh1,
    const float* __restrict__ wih2, const float* __restrict__ whh2,
    const float* __restrict__ bih2, const float* __restrict__ bhh2,
    unsigned* __restrict__ rec0, unsigned* __restrict__ rec1,
    unsigned* __restrict__ rec2, unsigned* __restrict__ xcdmap,
    float* __restrict__ hs2) {
  const int l = blockIdx.x & 7;
  if (l >= 3) return;                       // residues 3..7 idle
  const int blk = blockIdx.x >> 3;          // 0..31 within layer
  const int tid = threadIdx.x, wv = tid >> 6, lane = tid & 63;

  unsigned xcc;
  asm volatile("s_getreg_b32 %0, hwreg(20, 0, 32)" : "=s"(xcc));  // XCC_ID
  xcc &= 0xffu;
  if (tid == 0)
    __hip_atomic_store(&xcdmap[l * LSB + blk], 0x100u | xcc,
                       __ATOMIC_RELAXED, __HIP_MEMORY_SCOPE_AGENT);

  __shared__ unsigned hbuf32[320];   // 640 f16 h (own layer, t-1)
  __shared__ unsigned xbuf32[320];   // 640 f16 x (upstream, t)
  __shared__ float pdot[80];         // full row sums: idx = 20*g + d

  const float* Wih = (l == 1) ? wih1 : wih2;
  const float* Whh = (l == 0) ? whh0 : ((l == 1) ? whh1 : whh2);
  const float* bi  = (l == 1) ? bih1 : bih2;
  const float* bh  = (l == 1) ? bhh1 : bhh2;
  unsigned* recL = (l == 0) ? rec0 : ((l == 1) ? rec1 : rec2);
  const unsigned* recU = (l == 1) ? rec0 : rec1;

  // ---- stage weights into registers. wave wv: gate g=wv>>1, dims d0..d0+9.
  // lane k-chunk: [10*lane, 10*lane+10) as 5 packed f16 pairs.
  const int g = wv >> 1, d0 = 10 * (wv & 1);
  const int row0 = g * HD + blk * LDIM + d0;
  unsigned wh[10][5], wx[10][5];
#pragma unroll
  for (int ri = 0; ri < 10; ++ri) {
    const float* wr = Whh + (long)(row0 + ri) * HD + 10 * lane;
#pragma unroll
    for (int i = 0; i < 5; ++i) {
      float2 a = *(const float2*)(wr + 2 * i);
      wh[ri][i] = packh(a.x, a.y);
    }
  }
  if (l > 0) {
#pragma unroll
    for (int ri = 0; ri < 10; ++ri) {
      const float* wr = Wih + (long)(row0 + ri) * HD + 10 * lane;
#pragma unroll
      for (int i = 0; i < 5; ++i) {
        float2 a = *(const float2*)(wr + 2 * i);
        wx[ri][i] = packh(a.x, a.y);
      }
    }
  }

  // ---- gate lanes (wave 0, lane<20): per-dim external terms + cell state
  const int myd = blk * LDIM + lane;
  float ext[4] = {0.f, 0.f, 0.f, 0.f}, bsum[4] = {0.f, 0.f, 0.f, 0.f};
  float creg = 0.f;
  if (wv == 0 && lane < LDIM) {
    if (l == 0) {
#pragma unroll
      for (int q = 0; q < 4; ++q) ext[q] = xp[q * HD + myd];   // t = 0
    } else {
#pragma unroll
      for (int q = 0; q < 4; ++q) bsum[q] = bi[q * HD + myd] + bh[q * HD + myd];
    }
  }

  for (int i = tid; i < 320; i += 512) { hbuf32[i] = 0; xbuf32[i] = 0; }

  // ---- poll-lane geometry: wave wv covers dims [80*wv, 80*wv+80)
  // lanes 0..19 poll own layer (t-1); lanes 32..51 poll upstream (t), l>0.
  const bool isA = (lane < LDIM);
  const bool isB = (l > 0) && (lane >= 32) && (lane < 32 + LDIM);
  const int pp = isA ? lane : (lane - 32);
  const int dimoff = 80 * wv + 4 * pp;           // first of 4 polled h-dims
  const int srcblk = dimoff / LDIM;              // producing block
  const int sloto = dimoff + 12 * srcblk;        // padded slot in record row

  bool local = false;
  if (isA || isB) {
    const int maprow = isA ? l : (l - 1);
    const unsigned* me = &xcdmap[maprow * LSB + srcblk];
    unsigned e = 0;
    for (int c = 0; c < 100000; ++c) {
      e = __hip_atomic_load(me, __ATOMIC_RELAXED, __HIP_MEMORY_SCOPE_AGENT);
      if (e) break;
    }
    local = (e != 0) && ((e & 0xffu) == xcc);
  }
  __syncthreads();

  long totspins = 0;
  for (int t = 0; t < T_SEQ; ++t) {
    // ---- poll + unpack (own-layer lanes and upstream lanes in parallel)
    const bool want = (isA && t > 0) || isB;
    if (want && totspins < 30000000L) {
      const unsigned expseq = isA ? (unsigned)t : (unsigned)(t + 1);
      const unsigned* src = isA ? (recL + (long)(t - 1) * ROWU + sloto)
                                : (recU + (long)t * ROWU + sloto);
      unsigned* dst = (isA ? hbuf32 : xbuf32) + (dimoff >> 1);
      int ss = 0;
      for (;;) {
        u32x4 v;
        if (local) v = load16_sc0(src);
        else       v = load16_agent(src);
        if ((v.x >> 16) == expseq && (v.y >> 16) == expseq &&
            (v.z >> 16) == expseq && (v.w >> 16) == expseq) {
          dst[0] = (v.x & 0xffffu) | (v.y << 16);
          dst[1] = (v.z & 0xffffu) | (v.w << 16);
          break;
        }
        ++ss; ++totspins;
        if (ss > 4) __builtin_amdgcn_s_sleep(1);   // backoff (both paths)
        if (local && ss > 1024) local = false;     // escalate to agent scope
        if (totspins > 30000000L) break;           // safety: wrong > hung
      }
    }
    __syncthreads();   // hbuf/xbuf complete

    // ---- dot: 10 rows x full k; lane k-chunk [10*lane, 10*lane+10)
    unsigned hc[5], xc[5] = {0, 0, 0, 0, 0};
#pragma unroll
    for (int i = 0; i < 5; ++i) hc[i] = hbuf32[5 * lane + i];
    if (l > 0) {
#pragma unroll
      for (int i = 0; i < 5; ++i) xc[i] = xbuf32[5 * lane + i];
    }
    float sum[10];
#pragma unroll
    for (int ri = 0; ri < 10; ++ri) {
      float a = 0.f;
#pragma unroll
      for (int i = 0; i < 5; ++i) a = dot2acc(wh[ri][i], hc[i], a);
      if (l > 0) {
#pragma unroll
        for (int i = 0; i < 5; ++i) a = dot2acc(wx[ri][i], xc[i], a);
      }
      sum[ri] = wave_red(a);
    }
    if (lane == 63) {
#pragma unroll
      for (int ri = 0; ri < 10; ++ri) pdot[10 * wv + ri] = sum[ri];
    }
    __syncthreads();   // pdot ready

    // ---- gates: wave 0, lane<20 computes all 4 gates of its dim (no shfl)
    if (wv == 0 && lane < LDIM) {
      float gs[4];
#pragma unroll
      for (int q = 0; q < 4; ++q)
        gs[q] = pdot[q * LDIM + lane] + ((l == 0) ? ext[q] : bsum[q]);
      const float ai = 1.f / (1.f + __expf(-gs[0]));
      const float af = 1.f / (1.f + __expf(-gs[1]));
      const float eg = __expf(2.f * gs[2]);
      const float ag = 1.f - 2.f / (eg + 1.f);
      const float ao = 1.f / (1.f + __expf(-gs[3]));
      creg = af * creg + ai * ag;
      const float ec = __expf(2.f * creg);
      const float h = ao * (1.f - 2.f / (ec + 1.f));
      const unsigned val = (unsigned)f2h(h) | ((unsigned)(t + 1) << 16);
      unsigned* wp = recL + (long)t * ROWU + blk * 32 + lane;
      __hip_atomic_store(wp, val, __ATOMIC_RELAXED,
                         __HIP_MEMORY_SCOPE_AGENT);   // write-through L2 + IF
      if (l == 2) hs2[(long)t * HD + myd] = h;
      if (l == 0 && t + 1 < T_SEQ) {
#pragma unroll
        for (int q = 0; q < 4; ++q)
          ext[q] = xp[(long)(t + 1) * GD + q * HD + myd];       // prefetch
      }
    }
  }
}

// ---------------------------------------------------------------------------
// GCN pieces (unchanged)
// ---------------------------------------------------------------------------
__global__ __launch_bounds__(256) void gcn_gemm(
    const float* __restrict__ X, const float* __restrict__ W,
    float* __restrict__ Y, int di, int dout) {
  __shared__ float xr[640];
  const int n = blockIdx.x;
  for (int k = threadIdx.x; k < di; k += 256) xr[k] = X[(long)n * di + k];
  __syncthreads();
  for (int c = threadIdx.x; c < dout; c += 256) {
    float acc = 0.f;
    for (int k = 0; k < di; k++) acc = fmaf(xr[k], W[(long)k * dout + c], acc);
    Y[(long)n * dout + c] = acc;
  }
}

__global__ void deg_kernel(const int* __restrict__ dst, unsigned int* __restrict__ deg) {
  const int e = blockIdx.x * 256 + threadIdx.x;
  if (e < NEDGE) atomicAdd(&deg[dst[e]], 1u);
}

__global__ void dinv_kernel(const unsigned int* __restrict__ deg, float* __restrict__ dinv) {
  const int n = blockIdx.x * 256 + threadIdx.x;
  if (n < NNODES) dinv[n] = 1.f / sqrtf((float)(deg[n] + 1u));
}

__global__ __launch_bounds__(128) void gcn_scatter(
    const float* __restrict__ XW, const int* __restrict__ src,
    const int* __restrict__ dst, const float* __restrict__ dinv,
    float* __restrict__ out, int dout) {
  const int e = blockIdx.x;
  const int s = src[e], d = dst[e];
  const float nrm = dinv[s] * dinv[d];
  for (int c = threadIdx.x; c < dout; c += 128)
    atomicAdd(&out[(long)d * dout + c], XW[(long)s * dout + c] * nrm);
}

__global__ __launch_bounds__(256) void gcn_bn(
    const float* __restrict__ scat, const float* __restrict__ xw,
    const float* __restrict__ dinv, const float* __restrict__ bias,
    float* __restrict__ out, int dout) {
  const int c = blockIdx.x;
  const float bc = bias[c];
  float s = 0.f, s2 = 0.f;
  for (int n = threadIdx.x; n < NNODES; n += 256) {
    float v = scat[(long)n * dout + c] + xw[(long)n * dout + c] * dinv[n] * dinv[n] + bc;
    v = v >= 0.f ? v : 0.01f * v;
    s += v; s2 += v * v;
  }
  __shared__ float rs[4], rs2[4];
#pragma unroll
  for (int off = 32; off; off >>= 1) { s += __shfl_down(s, off, 64); s2 += __shfl_down(s2, off, 64); }
  const int w = threadIdx.x >> 6;
  if ((threadIdx.x & 63) == 0) { rs[w] = s; rs2[w] = s2; }
  __syncthreads();
  const float ts  = rs[0] + rs[1] + rs[2] + rs[3];
  const float ts2 = rs2[0] + rs2[1] + rs2[2] + rs2[3];
  const float mu = ts * (1.f / (float)NNODES);
  const float var = ts2 * (1.f / (float)NNODES) - mu * mu;
  const float rstd = 1.f / sqrtf(var + 1e-5f);
  for (int n = threadIdx.x; n < NNODES; n += 256) {
    float v = scat[(long)n * dout + c] + xw[(long)n * dout + c] * dinv[n] * dinv[n] + bc;
    v = v >= 0.f ? v : 0.01f * v;
    out[(long)n * dout + c] = (v - mu) * rstd;
  }
}

__global__ __launch_bounds__(64) void pool_kernel(
    const float* __restrict__ x, float* __restrict__ emb, float* __restrict__ dout) {
  const int g = blockIdx.x, c = threadIdx.x;
  if (c >= 50) return;
  float s = 0.f;
  for (int r = 0; r < 128; r++) s += x[(long)(g * 128 + r) * 50 + c];
  emb[g * 50 + c] = s;
  dout[16 + g * 50 + c] = s;
}

__global__ __launch_bounds__(64) void fc_head(
    const float* __restrict__ emb,
    const float* __restrict__ w1, const float* __restrict__ b1,
    const float* __restrict__ w2, const float* __restrict__ b2,
    const float* __restrict__ w3, const float* __restrict__ b3,
    float* __restrict__ dout) {
  const int g = threadIdx.x;
  if (g >= NGRAPH) return;
  float e[50];
#pragma unroll
  for (int k = 0; k < 50; k++) e[k] = emb[g * 50 + k];
  float t1[32];
  for (int j = 0; j < 32; j++) {
    float a = b1[j];
    for (int k = 0; k < 50; k++) a = fmaf(e[k], w1[k * 32 + j], a);
    t1[j] = a;
  }
  float t2[16];
  for (int j = 0; j < 16; j++) {
    float a = b2[j];
    for (int k = 0; k < 32; k++) a = fmaf(t1[k], w2[k * 16 + j], a);
    t2[j] = a;
  }
  float y = b3[0];
  for (int k = 0; k < 16; k++) y = fmaf(t2[k], w3[k], y);
  dout[g] = y;
}

// ---------------------------------------------------------------------------
extern "C" void kernel_launch(void* const* d_in, const int* in_sizes, int n_in,
                              void* d_out, int out_size, void* d_ws, size_t ws_size,
                              hipStream_t stream) {
  const float* x_in  = (const float*)d_in[0];
  const int*   eidx  = (const int*)d_in[1];
  const float* w_ih[3] = {(const float*)d_in[2], (const float*)d_in[6],  (const float*)d_in[10]};
  const float* w_hh[3] = {(const float*)d_in[3], (const float*)d_in[7],  (const float*)d_in[11]};
  const float* b_ih[3] = {(const float*)d_in[4], (const float*)d_in[8],  (const float*)d_in[12]};
  const float* b_hh[3] = {(const float*)d_in[5], (const float*)d_in[9],  (const float*)d_in[13]};
  const float* gw[4] = {(const float*)d_in[14], (const float*)d_in[16], (const float*)d_in[18], (const float*)d_in[20]};
  const float* gbv[4] = {(const float*)d_in[15], (const float*)d_in[17], (const float*)d_in[19], (const float*)d_in[21]};
  const float* fw1 = (const float*)d_in[22]; const float* fb1 = (const float*)d_in[23];
  const float* fw2 = (const float*)d_in[24]; const float* fb2 = (const float*)d_in[25];
  const float* fw3 = (const float*)d_in[26]; const float* fb3 = (const float*)d_in[27];
  const int* src = eidx;
  const int* dst = eidx + NEDGE;

  // workspace layout (floats)
  float* ws  = (float*)d_ws;
  float* xp  = ws;                                   // 5,242,880
  unsigned* rec0 = (unsigned*)(ws + 5242880);        // 2,097,152 u32 each
  unsigned* rec1 = rec0 + RECN;
  unsigned* rec2 = rec1 + RECN;
  float* hs2 = ws + 5242880 + 3 * RECN;              // 1,310,720
  unsigned int* deg = (unsigned int*)(hs2 + 1310720);
  float* dinv = (float*)(deg + 2048);
  float* emb  = dinv + 2048;
  unsigned* xcdmap = (unsigned*)(emb + 800);         // 96 u32
  // GCN buffers alias the (then-dead) xp region
  float* ga = xp;
  float* gb = xp + 655360;
  float* x0 = xp + 1310720;
  float* x1 = xp + 1966080;

  hipMemsetAsync(rec0, 0, (size_t)3 * RECN * sizeof(unsigned), stream);
  hipMemsetAsync(xcdmap, 0, 96 * sizeof(unsigned), stream);
  hipMemsetAsync(deg, 0, 2048 * sizeof(unsigned int), stream);

  gemm_mfma<<<dim3(GD / 128, NNODES / 128), 256, 0, stream>>>(
      x_in, w_ih[0], b_ih[0], b_hh[0], xp, NNODES, GD, KIN);

  deg_kernel<<<NEDGE / 256, 256, 0, stream>>>(dst, deg);
  dinv_kernel<<<NNODES / 256, 256, 0, stream>>>(deg, dinv);

  fused_scan<<<256, 512, 0, stream>>>(
      xp, w_hh[0], w_ih[1], w_hh[1], b_ih[1], b_hh[1],
      w_ih[2], w_hh[2], b_ih[2], b_hh[2],
      rec0, rec1, rec2, xcdmap, hs2);

  const int dims_in[4]  = {640, 320, 180, 90};
  const int dims_out[4] = {320, 180, 90, 50};
  const float* xin_l[4] = {hs2, x0, x1, x0};
  float* xout_l[4]      = {x0, x1, x0, x1};
  for (int l = 0; l < 4; l++) {
    gcn_gemm<<<NNODES, 256, 0, stream>>>(xin_l[l], gw[l], ga, dims_in[l], dims_out[l]);
    hipMemsetAsync(gb, 0, (size_t)NNODES * dims_out[l] * sizeof(float), stream);
    gcn_scatter<<<NEDGE, 128, 0, stream>>>(ga, src, dst, dinv, gb, dims_out[l]);
    gcn_bn<<<dims_out[l], 256, 0, stream>>>(gb, ga, dinv, gbv[l], xout_l[l], dims_out[l]);
  }

  pool_kernel<<<NGRAPH, 64, 0, stream>>>(x1, emb, (float*)d_out);
  fc_head<<<1, 64, 0, stream>>>(emb, fw1, fb1, fw2, fb2, fw3, fb3, (float*)d_out);
}

// Round 3
// 6133.816 us; speedup vs baseline: 6.2459x; 2.1871x over previous
//
#include <hip/hip_runtime.h>
#include <stdint.h>

#define NNODES 2048
#define T_SEQ  2048
#define HD     640
#define GD     2560   // 4*HD
#define KIN    8500
#define NEDGE  65536
#define NGRAPH 16

// fused_scan geometry: 3 layers x 80 blocks x 8 dims, 512 threads (8 waves).
// Record row: 80 records x 3 u64 (3 f16 h + 16-bit seq each) = 240 u64.
#define LSB    80     // blocks per layer
#define LDIM   8      // h-dims per block
#define ROW64  240    // u64 per timestep row
#define RECL   (T_SEQ * ROW64)   // u64 per layer record buffer

typedef unsigned long long u64;
typedef _Float16 half2v __attribute__((ext_vector_type(2)));
using short8 = __attribute__((ext_vector_type(8))) short;
using f32x4  = __attribute__((ext_vector_type(4))) float;

#if __has_builtin(__builtin_amdgcn_fdot2)
#define HAVE_FDOT2 1
#endif

__device__ __forceinline__ float dot2acc(unsigned w, unsigned h, float acc) {
#ifdef HAVE_FDOT2
  return __builtin_amdgcn_fdot2(__builtin_bit_cast(half2v, w),
                                __builtin_bit_cast(half2v, h), acc, false);
#else
  acc += (float)__builtin_bit_cast(_Float16, (unsigned short)(w & 0xffffu)) *
         (float)__builtin_bit_cast(_Float16, (unsigned short)(h & 0xffffu));
  acc += (float)__builtin_bit_cast(_Float16, (unsigned short)(w >> 16)) *
         (float)__builtin_bit_cast(_Float16, (unsigned short)(h >> 16));
  return acc;
#endif
}

__device__ __forceinline__ unsigned short f2h(float x) {
  return __builtin_bit_cast(unsigned short, (_Float16)x);
}
__device__ __forceinline__ unsigned packh(float a, float b) {
  return (unsigned)f2h(a) | ((unsigned)f2h(b) << 16);
}
__device__ __forceinline__ unsigned f2bf(float x) {
  unsigned u = __float_as_uint(x);
  return (u + 0x7fffu + ((u >> 16) & 1u)) >> 16;
}
__device__ __forceinline__ unsigned packbf(float a, float b) {
  return f2bf(a) | (f2bf(b) << 16);
}

// ---------------------------------------------------------------------------
// C[M,N] = A[M,K] @ W[N,K]^T + b1[n] + b2[n], bf16 MFMA 16x16x32. (unchanged)
// ---------------------------------------------------------------------------
#define GK 32
__global__ __launch_bounds__(256) void gemm_mfma(
    const float* __restrict__ A, const float* __restrict__ W,
    const float* __restrict__ b1, const float* __restrict__ b2,
    float* __restrict__ C, int M, int N, int K) {
  __shared__ __align__(16) short As[128 * 40];
  __shared__ __align__(16) short Ws[128 * 40];
  const int tid = threadIdx.x;
  const int wave = tid >> 6, lane = tid & 63;
  const int bm = blockIdx.y * 128, bn = blockIdx.x * 128;
  const int wm = (wave >> 1) * 64, wn = (wave & 1) * 64;
  const int mrow = lane & 15, quad = lane >> 4;
  const int srow = tid >> 1, skc = (tid & 1) * 16;
  f32x4 acc[4][4] = {};
  for (int k0 = 0; k0 < K; k0 += GK) {
    float av[16], wv[16];
    if (k0 + GK <= K) {
      const float* Ap = A + (long)(bm + srow) * K + k0 + skc;
      const float* Wp = W + (long)(bn + srow) * K + k0 + skc;
#pragma unroll
      for (int i = 0; i < 4; i++) {
        float4 a4 = *(const float4*)(Ap + 4 * i);
        float4 w4 = *(const float4*)(Wp + 4 * i);
        av[4*i]=a4.x; av[4*i+1]=a4.y; av[4*i+2]=a4.z; av[4*i+3]=a4.w;
        wv[4*i]=w4.x; wv[4*i+1]=w4.y; wv[4*i+2]=w4.z; wv[4*i+3]=w4.w;
      }
    } else {
#pragma unroll
      for (int i = 0; i < 16; i++) {
        const int k = k0 + skc + i;
        av[i] = (k < K) ? A[(long)(bm + srow) * K + k] : 0.f;
        wv[i] = (k < K) ? W[(long)(bn + srow) * K + k] : 0.f;
      }
    }
    __syncthreads();
    {
      uint4* pa = (uint4*)&As[srow * 40 + skc];
      uint4* pw = (uint4*)&Ws[srow * 40 + skc];
      pa[0] = make_uint4(packbf(av[0],av[1]), packbf(av[2],av[3]),
                         packbf(av[4],av[5]), packbf(av[6],av[7]));
      pa[1] = make_uint4(packbf(av[8],av[9]), packbf(av[10],av[11]),
                         packbf(av[12],av[13]), packbf(av[14],av[15]));
      pw[0] = make_uint4(packbf(wv[0],wv[1]), packbf(wv[2],wv[3]),
                         packbf(wv[4],wv[5]), packbf(wv[6],wv[7]));
      pw[1] = make_uint4(packbf(wv[8],wv[9]), packbf(wv[10],wv[11]),
                         packbf(wv[12],wv[13]), packbf(wv[14],wv[15]));
    }
    __syncthreads();
    short8 af[4], bf[4];
#pragma unroll
    for (int mi = 0; mi < 4; mi++)
      af[mi] = *(const short8*)&As[(wm + mi * 16 + mrow) * 40 + quad * 8];
#pragma unroll
    for (int ni = 0; ni < 4; ni++)
      bf[ni] = *(const short8*)&Ws[(wn + ni * 16 + mrow) * 40 + quad * 8];
#pragma unroll
    for (int mi = 0; mi < 4; mi++)
#pragma unroll
      for (int ni = 0; ni < 4; ni++)
        acc[mi][ni] = __builtin_amdgcn_mfma_f32_16x16x32_bf16(
            af[mi], bf[ni], acc[mi][ni], 0, 0, 0);
  }
#pragma unroll
  for (int ni = 0; ni < 4; ni++) {
    const int c = bn + wn + ni * 16 + mrow;
    const float bias = b1[c] + b2[c];
#pragma unroll
    for (int mi = 0; mi < 4; mi++) {
      const int r0 = bm + wm + mi * 16 + quad * 4;
#pragma unroll
      for (int reg = 0; reg < 4; reg++)
        C[(long)(r0 + reg) * N + c] = acc[mi][ni][reg] + bias;
    }
  }
}

// ---------------------------------------------------------------------------
// Fused 3-layer pipelined LSTM scan.
// 80 blocks/layer x 8 dims, 512 threads (8 waves). Weights in registers:
// lane (row=l&31, k-half=l>>5) holds 40 f16 hh + 40 f16 ih = 40 u32 VGPRs
// (total live ~100 — under the allocator's observed 112 target, so no spill;
// rounds 1-2 failed because 100-reg arrays + working set spilled).
// Per-step LDS traffic ~2 KB (vs round-0's 205 KB weight+vector re-read).
// Records: 3 u64 per block row (3 f16 h + seq<<48), agent-scope everywhere.
// One __syncthreads per step; pdot parity-double-buffered.
// ---------------------------------------------------------------------------
__global__ __launch_bounds__(512, 2) void fused_scan(
    const float* __restrict__ xp,
    const float* __restrict__ whh0,
    const float* __restrict__ wih1, const float* __restrict__ whh1,
    const float* __restrict__ bih1, const float* __restrict__ bhh1,
    const float* __restrict__ wih2, const float* __restrict__ whh2,
    const float* __restrict__ bih2, const float* __restrict__ bhh2,
    u64* __restrict__ rec0, u64* __restrict__ rec1, u64* __restrict__ rec2,
    float* __restrict__ hs2) {
  const int l = blockIdx.x / LSB, blk = blockIdx.x % LSB;
  const int tid = threadIdx.x, wv = tid >> 6, lane = tid & 63;

  __shared__ __align__(16) unsigned short hbufh[640];  // own-layer h (t-1)
  __shared__ __align__(16) unsigned short xbufh[640];  // upstream x (t)
  __shared__ float pdot[2][8][32];                     // [parity][wave][row]

  const float* Wih = (l == 1) ? wih1 : wih2;
  const float* Whh = (l == 0) ? whh0 : ((l == 1) ? whh1 : whh2);
  const float* bi  = (l == 1) ? bih1 : bih2;
  const float* bh  = (l == 1) ? bhh1 : bhh2;
  u64* recL = (l == 0) ? rec0 : ((l == 1) ? rec1 : rec2);
  const u64* recU = (l == 1) ? rec0 : rec1;

  // ---- stage weights into registers (small per-lane slice, one-time)
  const int r = lane & 31, kh = lane >> 5;     // row 0..31, k-half 0..1
  const int gq = r >> 3, dd = r & 7;           // gate, dim
  const long wro = (long)(gq * HD + blk * LDIM + dd) * HD + 80 * wv + 40 * kh;
  unsigned wh[20], wx[20];
#pragma unroll
  for (int i = 0; i < 10; ++i) {
    float4 a = *(const float4*)(Whh + wro + 4 * i);
    wh[2 * i]     = packh(a.x, a.y);
    wh[2 * i + 1] = packh(a.z, a.w);
  }
  if (l > 0) {
#pragma unroll
    for (int i = 0; i < 10; ++i) {
      float4 a = *(const float4*)(Wih + wro + 4 * i);
      wx[2 * i]     = packh(a.x, a.y);
      wx[2 * i + 1] = packh(a.z, a.w);
    }
  }

  // ---- gate-row external term (wave 0, lanes<32): xp row (l==0) or bias sum
  const int gidx = (lane >> 3) * HD + blk * LDIM + (lane & 7);
  float extb = 0.f, creg = 0.f;
  if (wv == 0 && lane < 32)
    extb = (l == 0) ? xp[gidx] : (bi[gidx] + bh[gidx]);

  // ---- zero own h slice (wave-private: dims [80*wv, 80*wv+80))
  unsigned* hbuf32 = (unsigned*)hbufh;
  unsigned* xbuf32 = (unsigned*)xbufh;
  if (lane < 40) { hbuf32[40 * wv + lane] = 0; xbuf32[40 * wv + lane] = 0; }
  __syncthreads();

  // ---- poll geometry: wave covers records [10*wv, 10*wv+10), 3 u64 each.
  // lanes 0..29 poll own layer (t-1); lanes 32..61 poll upstream (t), l>0.
  const bool isA = (lane < 30);
  const bool isB = (l > 0) && (lane >= 32) && (lane < 62);
  const int p = isA ? lane : (lane - 32);
  const int dimb = 80 * wv + (p / 3) * LDIM + 3 * (p % 3);
  const int ncnt = ((p % 3) == 2) ? 2 : 3;
  unsigned short* slot = (isA ? hbufh : xbufh) + dimb;

  long totspins = 0;
  for (int t = 0; t < T_SEQ; ++t) {
    // ---- poll + unpack
    const bool want = (isA && t > 0) || isB;
    if (want && totspins < 30000000L) {
      const u64* src = isA ? (recL + (long)(t - 1) * ROW64 + 30 * wv + p)
                           : (recU + (long)t * ROW64 + 30 * wv + p);
      const unsigned exps = isA ? (unsigned)t : (unsigned)(t + 1);
      int ss = 0;
      for (;;) {
        const u64 v = __hip_atomic_load(src, __ATOMIC_RELAXED,
                                        __HIP_MEMORY_SCOPE_AGENT);
        if ((unsigned)(v >> 48) == exps) {
          slot[0] = (unsigned short)v;
          slot[1] = (unsigned short)(v >> 16);
          if (ncnt == 3) slot[2] = (unsigned short)(v >> 32);
          break;
        }
        ++totspins;
        if (++ss > 2) __builtin_amdgcn_s_sleep(1);
        if (totspins > 30000000L) break;   // safety: wrong > hung
      }
    }
    __threadfence_block();   // order LDS unpack writes before same-wave reads

    // ---- dot: lane row r, k chunk [80*wv + 40*kh, +40)
    unsigned hc[20];
    {
      const uint4* hb = (const uint4*)&hbuf32[40 * wv + 20 * kh];
#pragma unroll
      for (int i = 0; i < 5; ++i) {
        uint4 q = hb[i];
        hc[4*i] = q.x; hc[4*i+1] = q.y; hc[4*i+2] = q.z; hc[4*i+3] = q.w;
      }
    }
    float a = 0.f;
#pragma unroll
    for (int i = 0; i < 20; ++i) a = dot2acc(wh[i], hc[i], a);
    if (l > 0) {
      const uint4* xb = (const uint4*)&xbuf32[40 * wv + 20 * kh];
#pragma unroll
      for (int i = 0; i < 5; ++i) {
        uint4 q = xb[i];
        hc[4*i] = q.x; hc[4*i+1] = q.y; hc[4*i+2] = q.z; hc[4*i+3] = q.w;
      }
#pragma unroll
      for (int i = 0; i < 20; ++i) a = dot2acc(wx[i], hc[i], a);
    }
    a += __shfl_xor(a, 32);                 // combine k-halves
    if (lane < 32) pdot[t & 1][wv][lane] = a;
    __syncthreads();   // pdot ready (single barrier per step)

    // ---- gates (wave 0, lanes<32 rows; lanes<8 cell/output)
    if (wv == 0) {
      const int par = t & 1;
      float av = 0.f;
      if (lane < 32) {
        float s = extb;
#pragma unroll
        for (int w = 0; w < 8; ++w) s += pdot[par][w][lane];
        if ((lane >> 3) == 2) {            // g gate: tanh
          const float e2 = __expf(2.f * s);
          av = 1.f - 2.f / (e2 + 1.f);
        } else {                           // i, f, o: sigmoid
          av = 1.f / (1.f + __expf(-s));
        }
      }
      const float ai = av;
      const float af = __shfl(av, lane + 8);
      const float ag = __shfl(av, lane + 16);
      const float ao = __shfl(av, lane + 24);
      float h = 0.f;
      if (lane < LDIM) {
        creg = af * creg + ai * ag;
        const float e2 = __expf(2.f * creg);
        h = ao * (1.f - 2.f / (e2 + 1.f));
        if (l == 2) hs2[(long)t * HD + blk * LDIM + lane] = h;
      }
      // pack 8 h into 3 u64 (3 f16 + seq each) and publish
      const float ha = __shfl(h, 3 * lane);
      const float hb2 = __shfl(h, 3 * lane + 1);
      const float hc2 = __shfl(h, 3 * lane + 2);
      if (lane < 3) {
        const unsigned seq = (unsigned)(t + 1);
        const u64 val = (u64)((unsigned)f2h(ha) | ((unsigned)f2h(hb2) << 16)) |
                        ((u64)((unsigned)f2h(hc2) | (seq << 16)) << 32);
        __hip_atomic_store(recL + (long)t * ROW64 + 3 * blk + lane, val,
                           __ATOMIC_RELAXED, __HIP_MEMORY_SCOPE_AGENT);
      }
      if (l == 0 && lane < 32 && t + 1 < T_SEQ)
        extb = xp[(long)(t + 1) * GD + gidx];   // prefetch next step
    }
  }
}

// ---------------------------------------------------------------------------
// GCN pieces (unchanged)
// ---------------------------------------------------------------------------
__global__ __launch_bounds__(256) void gcn_gemm(
    const float* __restrict__ X, const float* __restrict__ W,
    float* __restrict__ Y, int di, int dout) {
  __shared__ float xr[640];
  const int n = blockIdx.x;
  for (int k = threadIdx.x; k < di; k += 256) xr[k] = X[(long)n * di + k];
  __syncthreads();
  for (int c = threadIdx.x; c < dout; c += 256) {
    float acc = 0.f;
    for (int k = 0; k < di; k++) acc = fmaf(xr[k], W[(long)k * dout + c], acc);
    Y[(long)n * dout + c] = acc;
  }
}

__global__ void deg_kernel(const int* __restrict__ dst, unsigned int* __restrict__ deg) {
  const int e = blockIdx.x * 256 + threadIdx.x;
  if (e < NEDGE) atomicAdd(&deg[dst[e]], 1u);
}

__global__ void dinv_kernel(const unsigned int* __restrict__ deg, float* __restrict__ dinv) {
  const int n = blockIdx.x * 256 + threadIdx.x;
  if (n < NNODES) dinv[n] = 1.f / sqrtf((float)(deg[n] + 1u));
}

__global__ __launch_bounds__(128) void gcn_scatter(
    const float* __restrict__ XW, const int* __restrict__ src,
    const int* __restrict__ dst, const float* __restrict__ dinv,
    float* __restrict__ out, int dout) {
  const int e = blockIdx.x;
  const int s = src[e], d = dst[e];
  const float nrm = dinv[s] * dinv[d];
  for (int c = threadIdx.x; c < dout; c += 128)
    atomicAdd(&out[(long)d * dout + c], XW[(long)s * dout + c] * nrm);
}

__global__ __launch_bounds__(256) void gcn_bn(
    const float* __restrict__ scat, const float* __restrict__ xw,
    const float* __restrict__ dinv, const float* __restrict__ bias,
    float* __restrict__ out, int dout) {
  const int c = blockIdx.x;
  const float bc = bias[c];
  float s = 0.f, s2 = 0.f;
  for (int n = threadIdx.x; n < NNODES; n += 256) {
    float v = scat[(long)n * dout + c] + xw[(long)n * dout + c] * dinv[n] * dinv[n] + bc;
    v = v >= 0.f ? v : 0.01f * v;
    s += v; s2 += v * v;
  }
  __shared__ float rs[4], rs2[4];
#pragma unroll
  for (int off = 32; off; off >>= 1) { s += __shfl_down(s, off, 64); s2 += __shfl_down(s2, off, 64); }
  const int w = threadIdx.x >> 6;
  if ((threadIdx.x & 63) == 0) { rs[w] = s; rs2[w] = s2; }
  __syncthreads();
  const float ts  = rs[0] + rs[1] + rs[2] + rs[3];
  const float ts2 = rs2[0] + rs2[1] + rs2[2] + rs2[3];
  const float mu = ts * (1.f / (float)NNODES);
  const float var = ts2 * (1.f / (float)NNODES) - mu * mu;
  const float rstd = 1.f / sqrtf(var + 1e-5f);
  for (int n = threadIdx.x; n < NNODES; n += 256) {
    float v = scat[(long)n * dout + c] + xw[(long)n * dout + c] * dinv[n] * dinv[n] + bc;
    v = v >= 0.f ? v : 0.01f * v;
    out[(long)n * dout + c] = (v - mu) * rstd;
  }
}

__global__ __launch_bounds__(64) void pool_kernel(
    const float* __restrict__ x, float* __restrict__ emb, float* __restrict__ dout) {
  const int g = blockIdx.x, c = threadIdx.x;
  if (c >= 50) return;
  float s = 0.f;
  for (int r = 0; r < 128; r++) s += x[(long)(g * 128 + r) * 50 + c];
  emb[g * 50 + c] = s;
  dout[16 + g * 50 + c] = s;
}

__global__ __launch_bounds__(64) void fc_head(
    const float* __restrict__ emb,
    const float* __restrict__ w1, const float* __restrict__ b1,
    const float* __restrict__ w2, const float* __restrict__ b2,
    const float* __restrict__ w3, const float* __restrict__ b3,
    float* __restrict__ dout) {
  const int g = threadIdx.x;
  if (g >= NGRAPH) return;
  float e[50];
#pragma unroll
  for (int k = 0; k < 50; k++) e[k] = emb[g * 50 + k];
  float t1[32];
  for (int j = 0; j < 32; j++) {
    float a = b1[j];
    for (int k = 0; k < 50; k++) a = fmaf(e[k], w1[k * 32 + j], a);
    t1[j] = a;
  }
  float t2[16];
  for (int j = 0; j < 16; j++) {
    float a = b2[j];
    for (int k = 0; k < 32; k++) a = fmaf(t1[k], w2[k * 16 + j], a);
    t2[j] = a;
  }
  float y = b3[0];
  for (int k = 0; k < 16; k++) y = fmaf(t2[k], w3[k], y);
  dout[g] = y;
}

// ---------------------------------------------------------------------------
extern "C" void kernel_launch(void* const* d_in, const int* in_sizes, int n_in,
                              void* d_out, int out_size, void* d_ws, size_t ws_size,
                              hipStream_t stream) {
  const float* x_in  = (const float*)d_in[0];
  const int*   eidx  = (const int*)d_in[1];
  const float* w_ih[3] = {(const float*)d_in[2], (const float*)d_in[6],  (const float*)d_in[10]};
  const float* w_hh[3] = {(const float*)d_in[3], (const float*)d_in[7],  (const float*)d_in[11]};
  const float* b_ih[3] = {(const float*)d_in[4], (const float*)d_in[8],  (const float*)d_in[12]};
  const float* b_hh[3] = {(const float*)d_in[5], (const float*)d_in[9],  (const float*)d_in[13]};
  const float* gw[4] = {(const float*)d_in[14], (const float*)d_in[16], (const float*)d_in[18], (const float*)d_in[20]};
  const float* gbv[4] = {(const float*)d_in[15], (const float*)d_in[17], (const float*)d_in[19], (const float*)d_in[21]};
  const float* fw1 = (const float*)d_in[22]; const float* fb1 = (const float*)d_in[23];
  const float* fw2 = (const float*)d_in[24]; const float* fb2 = (const float*)d_in[25];
  const float* fw3 = (const float*)d_in[26]; const float* fb3 = (const float*)d_in[27];
  const int* src = eidx;
  const int* dst = eidx + NEDGE;

  // workspace layout (floats)
  float* ws  = (float*)d_ws;
  float* xp  = ws;                                   // 5,242,880 f
  u64* rec0 = (u64*)(ws + 5242880);                  // 491,520 u64 per layer
  u64* rec1 = rec0 + RECL;
  u64* rec2 = rec1 + RECL;
  float* hs2 = ws + 5242880 + 2949120;               // 1,310,720 f
  unsigned int* deg = (unsigned int*)(hs2 + 1310720);
  float* dinv = (float*)(deg + 2048);
  float* emb  = dinv + 2048;
  // GCN buffers alias the (then-dead) xp region
  float* ga = xp;
  float* gb = xp + 655360;
  float* x0 = xp + 1310720;
  float* x1 = xp + 1966080;

  // seq=0 in all records (expected seqs are >=1); zero deg
  hipMemsetAsync(rec0, 0, (size_t)3 * RECL * sizeof(u64), stream);
  hipMemsetAsync(deg, 0, 2048 * sizeof(unsigned int), stream);

  gemm_mfma<<<dim3(GD / 128, NNODES / 128), 256, 0, stream>>>(
      x_in, w_ih[0], b_ih[0], b_hh[0], xp, NNODES, GD, KIN);

  deg_kernel<<<NEDGE / 256, 256, 0, stream>>>(dst, deg);
  dinv_kernel<<<NNODES / 256, 256, 0, stream>>>(deg, dinv);

  fused_scan<<<3 * LSB, 512, 0, stream>>>(
      xp, w_hh[0], w_ih[1], w_hh[1], b_ih[1], b_hh[1],
      w_ih[2], w_hh[2], b_ih[2], b_hh[2], rec0, rec1, rec2, hs2);

  const int dims_in[4]  = {640, 320, 180, 90};
  const int dims_out[4] = {320, 180, 90, 50};
  const float* xin_l[4] = {hs2, x0, x1, x0};
  float* xout_l[4]      = {x0, x1, x0, x1};
  for (int l = 0; l < 4; l++) {
    gcn_gemm<<<NNODES, 256, 0, stream>>>(xin_l[l], gw[l], ga, dims_in[l], dims_out[l]);
    hipMemsetAsync(gb, 0, (size_t)NNODES * dims_out[l] * sizeof(float), stream);
    gcn_scatter<<<NEDGE, 128, 0, stream>>>(ga, src, dst, dinv, gb, dims_out[l]);
    gcn_bn<<<dims_out[l], 256, 0, stream>>>(gb, ga, dinv, gbv[l], xout_l[l], dims_out[l]);
  }

  pool_kernel<<<NGRAPH, 64, 0, stream>>>(x1, emb, (float*)d_out);
  fc_head<<<1, 64, 0, stream>>>(emb, fw1, fb1, fw2, fb2, fw3, fb3, (float*)d_out);
}